// Round 2
// baseline (652.048 us; speedup 1.0000x reference)
//
#include <hip/hip_runtime.h>

#define TAU_INV 2.0f
#define R_ 5
#define NU 50000
#define NM 20000
#define EDGES 100000
#define F_ 4
#define D_ 16
#define DR 64
#define OUT_ 64

__device__ __forceinline__ float red16(float v) {
    v += __shfl_xor(v, 1);
    v += __shfl_xor(v, 2);
    v += __shfl_xor(v, 4);
    v += __shfl_xor(v, 8);
    return v;
}

// One wave (64 lanes) per edge. Computes gating weight w, accumulates segment norms.
__global__ __launch_bounds__(256) void k_edge_w(
    const float* __restrict__ ufk, const float* __restrict__ mfk,
    const float* __restrict__ ufs, const float* __restrict__ mfs,
    const float* __restrict__ rfeat, const float* __restrict__ proto,
    const float* __restrict__ eta, const int* __restrict__ eu,
    const int* __restrict__ em, const int* __restrict__ kp,
    float* __restrict__ wbuf, float* __restrict__ nrm_u, float* __restrict__ nrm_m)
{
    const int wv = threadIdx.x >> 6, l = threadIdx.x & 63;
    const int e = blockIdx.x * 4 + wv;
    if (e >= EDGES) return;
    const int r = blockIdx.y;
    const int idx = r * EDGES + e;
    const int u = eu[idx], m = em[idx];
    const int kk = kp[0];

    // ---- sim_all: per-f dot over d (flat F*d = 64, lane l -> f = l>>4) ----
    float a = ufs[(size_t)(r * NU + u) * 64 + l] * mfs[(size_t)(r * NM + m) * 64 + l];
    a = red16(a);                       // each lane: raw dot sim_all[f]
    float es = expf(a * TAU_INV);
    float dsim = es + __shfl_xor(es, 16);
    dsim += __shfl_xor(dsim, 32);       // sum_f exp(sim_all[f]/TAU), all lanes

    // ---- sim_k: l2norm'd dot over d=16 (groups redundant) ----
    float uk = ufk[(size_t)(r * NU + u) * 16 + (l & 15)];
    float mk = mfk[(size_t)(r * NM + m) * 16 + (l & 15)];
    float su = red16(uk * uk);
    float sm = red16(mk * mk);
    float sd = red16(uk * mk);
    float nsim = expf(sd / (fmaxf(sqrtf(su), 1e-12f) * fmaxf(sqrtf(sm), 1e-12f)) * TAU_INV);

    // ---- anchor: review_feat row (F*Dr = 256 floats, coalesced float4/lane) ----
    const float4 rf = ((const float4*)(rfeat + (size_t)idx * 256))[l];
    const float4 pr = ((const float4*)proto)[l];
    float ap = rf.x * pr.x + rf.y * pr.y + rf.z * pr.z + rf.w * pr.w;
    ap = red16(ap);                     // lane -> ad_all[f=l>>4] (raw dot)
    float ea = expf(ap * TAU_INV);
    float dan = ea + __shfl_xor(ea, 16);
    dan += __shfl_xor(dan, 32);
    float adk = __shfl(ap, kk << 4);    // ad_all[k]
    float na = expf(adk * TAU_INV);

    float g = 1.0f / (1.0f + expf(-eta[idx]));
    float w = g * (na / dan) + (1.0f - g) * (nsim / dsim);

    if (l == 0) {
        wbuf[idx] = w;
        atomicAdd(&nrm_u[u], w);
        atomicAdd(&nrm_m[m], w);
    }
}

// One wave per edge: message = (h_node + review_proj) * w_norm, scattered via atomics.
__global__ __launch_bounds__(256) void k_edge_msg(
    const float* __restrict__ ufk, const float* __restrict__ mfk,
    const float* __restrict__ rfeat,
    const float* __restrict__ nwf, const float* __restrict__ rwf,
    const float* __restrict__ nwr, const float* __restrict__ rwr,
    const int* __restrict__ eu, const int* __restrict__ em, const int* __restrict__ kp,
    const float* __restrict__ wbuf, const float* __restrict__ nrm_u,
    const float* __restrict__ nrm_m,
    float* __restrict__ upre, float* __restrict__ ipre, float* __restrict__ dist_out)
{
    __shared__ float s_wf[256], s_wr[256];     // [d][o] transposed
    __shared__ float s_rwf[1024], s_rwr[1024]; // [dr][o] transposed
    __shared__ float s_rf[4][64], s_uf[4][16], s_mf[4][16];

    const int tid = threadIdx.x;
    const int r = blockIdx.y;

    // stage weights (transposed to [in][out] for conflict-lite reads)
    {
        int o = tid >> 4, dd = tid & 15;
        s_wf[dd * 16 + o] = nwf[r * 256 + tid];
        s_wr[dd * 16 + o] = nwr[r * 256 + tid];
    }
    for (int i = tid; i < 1024; i += 256) {
        int o = i >> 6, dr = i & 63;
        s_rwf[dr * 16 + o] = rwf[r * 1024 + i];
        s_rwr[dr * 16 + o] = rwr[r * 1024 + i];
    }

    const int wv = tid >> 6, l = tid & 63;
    const int e = blockIdx.x * 4 + wv;
    const int idx = r * EDGES + e;
    bool live = (e < EDGES);
    int u = 0, m = 0;
    const int kk = kp[0];
    float wn = 0.f;

    if (live) {
        u = eu[idx]; m = em[idx];
        s_rf[wv][l] = rfeat[((size_t)idx * 4 + kk) * 64 + l];
        if (l < 16) {
            s_uf[wv][l] = ufk[(size_t)(r * NU + u) * 16 + l];
            s_mf[wv][l] = mfk[(size_t)(r * NM + m) * 16 + l];
        }
        const float w = wbuf[idx];
        wn = w / sqrtf(nrm_u[u] * nrm_m[m]);
        if (l == 0) dist_out[idx] = wn;
    }

    __syncthreads();
    if (!live) return;

    const int o = l & 15, q = l >> 4;
    float am = 0.f, au = 0.f;
#pragma unroll
    for (int t = 0; t < 16; t++) {
        const float rv = s_rf[wv][q * 16 + t];
        am += rv * s_rwf[(q * 16 + t) * 16 + o];
        au += rv * s_rwr[(q * 16 + t) * 16 + o];
    }
#pragma unroll
    for (int j = 0; j < 4; j++) {
        const int dd = q * 4 + j;
        am += s_uf[wv][dd] * s_wf[dd * 16 + o];
        au += s_mf[wv][dd] * s_wr[dd * 16 + o];
    }
    am += __shfl_xor(am, 16); am += __shfl_xor(am, 32);
    au += __shfl_xor(au, 16); au += __shfl_xor(au, 32);
    am *= wn; au *= wn;

    if (l < 16)       atomicAdd(&ipre[(size_t)m * 16 + o], am);
    else if (l < 32)  atomicAdd(&upre[(size_t)u * 16 + o], au);
}

// Fused leaky-relu + (N,16) x (16,64) FC for both tables.
__global__ __launch_bounds__(256) void k_fc(
    const float* __restrict__ upre, const float* __restrict__ ipre,
    const float* __restrict__ uw, const float* __restrict__ ub,
    const float* __restrict__ iw, const float* __restrict__ ib,
    float* __restrict__ out_u, float* __restrict__ out_i)
{
    const int tid = threadIdx.x;
    const int n = blockIdx.x * 4 + (tid >> 6);
    if (n >= NU + NM) return;
    const int o = tid & 63;
    const float* pre; const float* W; const float* B; float* dst;
    if (n < NU) { pre = upre + (size_t)n * 16; W = uw; B = ub; dst = out_u + (size_t)n * 64; }
    else { int n2 = n - NU; pre = ipre + (size_t)n2 * 16; W = iw; B = ib; dst = out_i + (size_t)n2 * 64; }
    float acc = B[o];
#pragma unroll
    for (int d = 0; d < 16; d++) {
        float x = pre[d];
        x = x >= 0.f ? x : 0.1f * x;
        acc += x * W[o * 16 + d];
    }
    dst[o] = acc;
}

extern "C" void kernel_launch(void* const* d_in, const int* in_sizes, int n_in,
                              void* d_out, int out_size, void* d_ws, size_t ws_size,
                              hipStream_t stream) {
    const float* ufk  = (const float*)d_in[0];
    const float* mfk  = (const float*)d_in[1];
    const float* ufs  = (const float*)d_in[2];
    const float* mfs  = (const float*)d_in[3];
    const float* rfe  = (const float*)d_in[4];
    const float* pro  = (const float*)d_in[5];
    const float* eta  = (const float*)d_in[6];
    const float* nwf  = (const float*)d_in[7];
    const float* rwf  = (const float*)d_in[8];
    const float* nwr  = (const float*)d_in[9];
    const float* rwr  = (const float*)d_in[10];
    const float* uw   = (const float*)d_in[11];
    const float* ub   = (const float*)d_in[12];
    const float* iw   = (const float*)d_in[13];
    const float* ib   = (const float*)d_in[14];
    const int*   eu   = (const int*)d_in[15];
    const int*   em   = (const int*)d_in[16];
    const int*   kp   = (const int*)d_in[17];

    float* out    = (float*)d_out;
    float* out_u  = out;                         // NU*64
    float* out_i  = out + (size_t)NU * 64;       // NM*64
    float* out_d  = out_i + (size_t)NM * 64;     // R*E

    float* ws    = (float*)d_ws;
    float* nrm_u = ws;                           // NU
    float* nrm_m = nrm_u + NU;                   // NM
    float* upre  = nrm_m + NM;                   // NU*16
    float* ipre  = upre + (size_t)NU * 16;       // NM*16
    float* wbuf  = ipre + (size_t)NM * 16;       // R*E

    const size_t zeroN = (size_t)NU + NM + (size_t)NU * 16 + (size_t)NM * 16;
    hipMemsetAsync(d_ws, 0, zeroN * sizeof(float), stream);

    dim3 gE((EDGES + 3) / 4, R_);
    k_edge_w<<<gE, 256, 0, stream>>>(ufk, mfk, ufs, mfs, rfe, pro, eta, eu, em, kp,
                                     wbuf, nrm_u, nrm_m);
    k_edge_msg<<<gE, 256, 0, stream>>>(ufk, mfk, rfe, nwf, rwf, nwr, rwr, eu, em, kp,
                                       wbuf, nrm_u, nrm_m, upre, ipre, out_d);
    k_fc<<<((NU + NM) + 3) / 4, 256, 0, stream>>>(upre, ipre, uw, ub, iw, ib, out_u, out_i);
}

// Round 5
// 437.781 us; speedup vs baseline: 1.4894x; 1.4894x over previous
//
#include <hip/hip_runtime.h>

#define TAU_INV 2.0f
#define R_ 5
#define NU 50000
#define NM 20000
#define EDGES 100000
#define F_ 4
#define D_ 16
#define DR 64
#define OUT_ 64
#define EPW 8   // edges per wave in k_edge_msg

__device__ __forceinline__ float red16(float v) {
    v += __shfl_xor(v, 1);
    v += __shfl_xor(v, 2);
    v += __shfl_xor(v, 4);
    v += __shfl_xor(v, 8);
    return v;
}

__device__ __forceinline__ float dot4(float4 a, float4 b) {
    return a.x * b.x + a.y * b.y + a.z * b.z + a.w * b.w;
}

// One wave (64 lanes) per edge. Computes gating weight w, accumulates segment norms.
__global__ __launch_bounds__(256) void k_edge_w(
    const float* __restrict__ ufk, const float* __restrict__ mfk,
    const float* __restrict__ ufs, const float* __restrict__ mfs,
    const float* __restrict__ rfeat, const float* __restrict__ proto,
    const float* __restrict__ eta, const int* __restrict__ eu,
    const int* __restrict__ em, const int* __restrict__ kp,
    float* __restrict__ wbuf, float* __restrict__ nrm_u, float* __restrict__ nrm_m)
{
    const int wv = threadIdx.x >> 6, l = threadIdx.x & 63;
    const int e = blockIdx.x * 4 + wv;
    if (e >= EDGES) return;
    const int r = blockIdx.y;
    const int idx = r * EDGES + e;
    const int u = eu[idx], m = em[idx];
    const int kk = kp[0];

    // ---- sim_all: per-f dot over d (flat F*d = 64, lane l -> f = l>>4) ----
    float a = ufs[(size_t)(r * NU + u) * 64 + l] * mfs[(size_t)(r * NM + m) * 64 + l];
    a = red16(a);                       // each lane: raw dot sim_all[f]
    float es = expf(a * TAU_INV);
    float dsim = es + __shfl_xor(es, 16);
    dsim += __shfl_xor(dsim, 32);       // sum_f exp(sim_all[f]/TAU), all lanes

    // ---- sim_k: l2norm'd dot over d=16 (groups redundant) ----
    float uk = ufk[(size_t)(r * NU + u) * 16 + (l & 15)];
    float mk = mfk[(size_t)(r * NM + m) * 16 + (l & 15)];
    float su = red16(uk * uk);
    float sm = red16(mk * mk);
    float sd = red16(uk * mk);
    float nsim = expf(sd / (fmaxf(sqrtf(su), 1e-12f) * fmaxf(sqrtf(sm), 1e-12f)) * TAU_INV);

    // ---- anchor: review_feat row (F*Dr = 256 floats, coalesced float4/lane) ----
    const float4 rf = ((const float4*)(rfeat + (size_t)idx * 256))[l];
    const float4 pr = ((const float4*)proto)[l];
    float ap = dot4(rf, pr);
    ap = red16(ap);                     // lane -> ad_all[f=l>>4] (raw dot)
    float ea = expf(ap * TAU_INV);
    float dan = ea + __shfl_xor(ea, 16);
    dan += __shfl_xor(dan, 32);
    float adk = __shfl(ap, kk << 4);    // ad_all[k]
    float na = expf(adk * TAU_INV);

    float g = 1.0f / (1.0f + expf(-eta[idx]));
    float w = g * (na / dan) + (1.0f - g) * (nsim / dsim);

    if (l == 0) {
        wbuf[idx] = w;
        atomicAdd(&nrm_u[u], w);
        atomicAdd(&nrm_m[m], w);
    }
}

// One wave per EPW edges. All weights in registers (lane (o,q) owns its 40-float
// slice). rf_k / gathered node feats read directly from global (broadcast within
// q-groups, lines fetched once). No LDS -> no bank conflicts, no __syncthreads.
__global__ __launch_bounds__(256) void k_edge_msg(
    const float* __restrict__ ufk, const float* __restrict__ mfk,
    const float* __restrict__ rfeat,
    const float* __restrict__ nwf, const float* __restrict__ rwf,
    const float* __restrict__ nwr, const float* __restrict__ rwr,
    const int* __restrict__ eu, const int* __restrict__ em, const int* __restrict__ kp,
    const float* __restrict__ wbuf, const float* __restrict__ nrm_u,
    const float* __restrict__ nrm_m,
    float* __restrict__ upre, float* __restrict__ ipre, float* __restrict__ dist_out)
{
    const int tid = threadIdx.x;
    const int wv = tid >> 6, l = tid & 63;
    const int o = l & 15, q = l >> 4;
    const int r = blockIdx.y;
    const int kk = kp[0];

    // weights for (output o, input-quarter q) in registers
    const float4* pwf = (const float4*)(rwf + (size_t)r * 1024 + o * 64 + q * 16);
    const float4* pwr = (const float4*)(rwr + (size_t)r * 1024 + o * 64 + q * 16);
    const float4 wf0 = pwf[0], wf1 = pwf[1], wf2 = pwf[2], wf3 = pwf[3];
    const float4 wr0 = pwr[0], wr1 = pwr[1], wr2 = pwr[2], wr3 = pwr[3];
    const float4 nf = *(const float4*)(nwf + r * 256 + o * 16 + q * 4);
    const float4 nr = *(const float4*)(nwr + r * 256 + o * 16 + q * 4);

    const int ebase = (blockIdx.x * 4 + wv) * EPW;
    for (int j = 0; j < EPW; ++j) {
        const int e = ebase + j;
        if (e >= EDGES) break;
        const int idx = r * EDGES + e;
        const int u = eu[idx], m = em[idx];
        const float w = wbuf[idx];
        const float wn = w / sqrtf(nrm_u[u] * nrm_m[m]);

        const float4* rf4 = (const float4*)(rfeat + ((size_t)idx * 4 + kk) * 64 + q * 16);
        const float4 a0 = rf4[0], a1 = rf4[1], a2 = rf4[2], a3 = rf4[3];
        const float4 uf = *(const float4*)(ufk + (size_t)(r * NU + u) * 16 + q * 4);
        const float4 mf = *(const float4*)(mfk + (size_t)(r * NM + m) * 16 + q * 4);

        float am = dot4(a0, wf0) + dot4(a1, wf1) + dot4(a2, wf2) + dot4(a3, wf3)
                 + dot4(uf, nf);
        float au = dot4(a0, wr0) + dot4(a1, wr1) + dot4(a2, wr2) + dot4(a3, wr3)
                 + dot4(mf, nr);
        am += __shfl_xor(am, 16); am += __shfl_xor(am, 32);
        au += __shfl_xor(au, 16); au += __shfl_xor(au, 32);
        am *= wn; au *= wn;

        if (l == 0) dist_out[idx] = wn;
        if (l < 16)       atomicAdd(&ipre[(size_t)m * 16 + o], am);
        else if (l < 32)  atomicAdd(&upre[(size_t)u * 16 + o], au);
    }
}

// Fused leaky-relu + (N,16) x (16,64) FC for both tables.
__global__ __launch_bounds__(256) void k_fc(
    const float* __restrict__ upre, const float* __restrict__ ipre,
    const float* __restrict__ uw, const float* __restrict__ ub,
    const float* __restrict__ iw, const float* __restrict__ ib,
    float* __restrict__ out_u, float* __restrict__ out_i)
{
    const int tid = threadIdx.x;
    const int n = blockIdx.x * 4 + (tid >> 6);
    if (n >= NU + NM) return;
    const int o = tid & 63;
    const float* pre; const float* W; const float* B; float* dst;
    if (n < NU) { pre = upre + (size_t)n * 16; W = uw; B = ub; dst = out_u + (size_t)n * 64; }
    else { int n2 = n - NU; pre = ipre + (size_t)n2 * 16; W = iw; B = ib; dst = out_i + (size_t)n2 * 64; }
    float acc = B[o];
#pragma unroll
    for (int d = 0; d < 16; d++) {
        float x = pre[d];
        x = x >= 0.f ? x : 0.1f * x;
        acc += x * W[o * 16 + d];
    }
    dst[o] = acc;
}

extern "C" void kernel_launch(void* const* d_in, const int* in_sizes, int n_in,
                              void* d_out, int out_size, void* d_ws, size_t ws_size,
                              hipStream_t stream) {
    const float* ufk  = (const float*)d_in[0];
    const float* mfk  = (const float*)d_in[1];
    const float* ufs  = (const float*)d_in[2];
    const float* mfs  = (const float*)d_in[3];
    const float* rfe  = (const float*)d_in[4];
    const float* pro  = (const float*)d_in[5];
    const float* eta  = (const float*)d_in[6];
    const float* nwf  = (const float*)d_in[7];
    const float* rwf  = (const float*)d_in[8];
    const float* nwr  = (const float*)d_in[9];
    const float* rwr  = (const float*)d_in[10];
    const float* uw   = (const float*)d_in[11];
    const float* ub   = (const float*)d_in[12];
    const float* iw   = (const float*)d_in[13];
    const float* ib   = (const float*)d_in[14];
    const int*   eu   = (const int*)d_in[15];
    const int*   em   = (const int*)d_in[16];
    const int*   kp   = (const int*)d_in[17];

    float* out    = (float*)d_out;
    float* out_u  = out;                         // NU*64
    float* out_i  = out + (size_t)NU * 64;       // NM*64
    float* out_d  = out_i + (size_t)NM * 64;     // R*E

    float* ws    = (float*)d_ws;
    float* nrm_u = ws;                           // NU
    float* nrm_m = nrm_u + NU;                   // NM
    float* upre  = nrm_m + NM;                   // NU*16
    float* ipre  = upre + (size_t)NU * 16;       // NM*16
    float* wbuf  = ipre + (size_t)NM * 16;       // R*E

    const size_t zeroN = (size_t)NU + NM + (size_t)NU * 16 + (size_t)NM * 16;
    hipMemsetAsync(d_ws, 0, zeroN * sizeof(float), stream);

    dim3 gW((EDGES + 3) / 4, R_);
    k_edge_w<<<gW, 256, 0, stream>>>(ufk, mfk, ufs, mfs, rfe, pro, eta, eu, em, kp,
                                     wbuf, nrm_u, nrm_m);
    dim3 gM((EDGES + 4 * EPW - 1) / (4 * EPW), R_);
    k_edge_msg<<<gM, 256, 0, stream>>>(ufk, mfk, rfe, nwf, rwf, nwr, rwr, eu, em, kp,
                                       wbuf, nrm_u, nrm_m, upre, ipre, out_d);
    k_fc<<<((NU + NM) + 3) / 4, 256, 0, stream>>>(upre, ipre, uw, ub, iw, ib, out_u, out_i);
}

// Round 6
// 417.705 us; speedup vs baseline: 1.5610x; 1.0481x over previous
//
#include <hip/hip_runtime.h>

#define TAU_INV 2.0f
#define R_ 5
#define NU 50000
#define NM 20000
#define EDGES 100000
#define F_ 4
#define D_ 16
#define DR 64
#define OUT_ 64
#define EPW 8   // edges per wave in k_edge_msg

__device__ __forceinline__ float red16(float v) {
    v += __shfl_xor(v, 1);
    v += __shfl_xor(v, 2);
    v += __shfl_xor(v, 4);
    v += __shfl_xor(v, 8);
    return v;
}

__device__ __forceinline__ float dot4(float4 a, float4 b) {
    return a.x * b.x + a.y * b.y + a.z * b.z + a.w * b.w;
}

// One wave (64 lanes) per edge. Computes gating weight w, accumulates segment norms.
__global__ __launch_bounds__(256) void k_edge_w(
    const float* __restrict__ ufk, const float* __restrict__ mfk,
    const float* __restrict__ ufs, const float* __restrict__ mfs,
    const float* __restrict__ rfeat, const float* __restrict__ proto,
    const float* __restrict__ eta, const int* __restrict__ eu,
    const int* __restrict__ em, const int* __restrict__ kp,
    float* __restrict__ wbuf, float* __restrict__ nrm_u, float* __restrict__ nrm_m)
{
    const int wv = threadIdx.x >> 6, l = threadIdx.x & 63;
    const int e = blockIdx.x * 4 + wv;
    if (e >= EDGES) return;
    const int r = blockIdx.y;
    const int idx = r * EDGES + e;
    const int u = eu[idx], m = em[idx];
    const int kk = kp[0];

    // ---- sim_all: per-f dot over d (flat F*d = 64, lane l -> f = l>>4) ----
    float a = ufs[(size_t)(r * NU + u) * 64 + l] * mfs[(size_t)(r * NM + m) * 64 + l];
    a = red16(a);                       // each lane: raw dot sim_all[f]
    float es = expf(a * TAU_INV);
    float dsim = es + __shfl_xor(es, 16);
    dsim += __shfl_xor(dsim, 32);       // sum_f exp(sim_all[f]/TAU), all lanes

    // ---- sim_k: l2norm'd dot over d=16 (groups redundant) ----
    float uk = ufk[(size_t)(r * NU + u) * 16 + (l & 15)];
    float mk = mfk[(size_t)(r * NM + m) * 16 + (l & 15)];
    float su = red16(uk * uk);
    float sm = red16(mk * mk);
    float sd = red16(uk * mk);
    float nsim = expf(sd / (fmaxf(sqrtf(su), 1e-12f) * fmaxf(sqrtf(sm), 1e-12f)) * TAU_INV);

    // ---- anchor: review_feat row (F*Dr = 256 floats, coalesced float4/lane) ----
    const float4 rf = ((const float4*)(rfeat + (size_t)idx * 256))[l];
    const float4 pr = ((const float4*)proto)[l];
    float ap = dot4(rf, pr);
    ap = red16(ap);                     // lane -> ad_all[f=l>>4] (raw dot)
    float ea = expf(ap * TAU_INV);
    float dan = ea + __shfl_xor(ea, 16);
    dan += __shfl_xor(dan, 32);
    float adk = __shfl(ap, kk << 4);    // ad_all[k]
    float na = expf(adk * TAU_INV);

    float g = 1.0f / (1.0f + expf(-eta[idx]));
    float w = g * (na / dan) + (1.0f - g) * (nsim / dsim);

    if (l == 0) {
        wbuf[idx] = w;
        atomicAdd(&nrm_u[u], w);
        atomicAdd(&nrm_m[m], w);
    }
}

// One wave per EPW edges. Weights in registers. Per-edge data (rf row, ufk, mfk)
// staged coalesced into wave-private double-buffered LDS (24 lanes x 16B, zero
// redundancy), next edge's global loads issued before current edge's compute.
// LDS reads are 16-lane broadcasts / 2-way bank (free). One 32-lane atomic instr.
__global__ __launch_bounds__(256) void k_edge_msg(
    const float* __restrict__ ufk, const float* __restrict__ mfk,
    const float* __restrict__ rfeat,
    const float* __restrict__ nwf, const float* __restrict__ rwf,
    const float* __restrict__ nwr, const float* __restrict__ rwr,
    const int* __restrict__ eu, const int* __restrict__ em, const int* __restrict__ kp,
    const float* __restrict__ wbuf, const float* __restrict__ nrm_u,
    const float* __restrict__ nrm_m,
    float* __restrict__ upre, float* __restrict__ ipre, float* __restrict__ dist_out)
{
    __shared__ __align__(16) float lds[4][2][96]; // per wave, dbuf: rf[64] | ufk[16] | mfk[16]

    const int tid = threadIdx.x;
    const int wv = tid >> 6, l = tid & 63;
    const int o = l & 15, q = l >> 4;
    const int r = blockIdx.y;
    const int kk = kp[0];
    const int rE = r * EDGES;

    // weights for (output o, input-quarter q) in registers
    const float4* pwf = (const float4*)(rwf + (size_t)r * 1024 + o * 64 + q * 16);
    const float4* pwr = (const float4*)(rwr + (size_t)r * 1024 + o * 64 + q * 16);
    const float4 wf0 = pwf[0], wf1 = pwf[1], wf2 = pwf[2], wf3 = pwf[3];
    const float4 wr0 = pwr[0], wr1 = pwr[1], wr2 = pwr[2], wr3 = pwr[3];
    const float4 nf = *(const float4*)(nwf + r * 256 + o * 16 + q * 4);
    const float4 nr = *(const float4*)(nwr + r * 256 + o * 16 + q * 4);

    const int ebase = (blockIdx.x * 4 + wv) * EPW;

    // vectorized per-wave header loads: lane j holds edge ebase+j's ids/weight
    int eu8 = 0, em8 = 0; float w8 = 0.f;
    if (l < EPW) {
        int e2 = ebase + l; if (e2 >= EDGES) e2 = EDGES - 1;
        eu8 = eu[rE + e2]; em8 = em[rE + e2]; w8 = wbuf[rE + e2];
    }

    // ---- stage edge 0 into buffer 0 ----
    int u_n = __shfl(eu8, 0), m_n = __shfl(em8, 0);
    {
        float4 stg;
        int e0 = ebase; if (e0 >= EDGES) e0 = EDGES - 1;
        if (l < 16)      stg = ((const float4*)(rfeat + ((size_t)(rE + e0) * 4 + kk) * 64))[l];
        else if (l < 20) stg = ((const float4*)(ufk + (size_t)(r * NU + u_n) * 16))[l - 16];
        else if (l < 24) stg = ((const float4*)(mfk + (size_t)(r * NM + m_n) * 16))[l - 20];
        if (l < 24) ((float4*)&lds[wv][0][0])[l] = stg;
    }

    float wn8 = 0.f;  // lane j keeps edge j's wn for the batched dist write

#pragma unroll
    for (int j = 0; j < EPW; ++j) {
        const int u = u_n, m = m_n;
        const bool live = (ebase + j) < EDGES;

        // issue next edge's global loads early (ds_write deferred to loop bottom)
        float4 stg;
        if (j + 1 < EPW) {
            u_n = __shfl(eu8, j + 1); m_n = __shfl(em8, j + 1);
            int e1 = ebase + j + 1; if (e1 >= EDGES) e1 = EDGES - 1;
            if (l < 16)      stg = ((const float4*)(rfeat + ((size_t)(rE + e1) * 4 + kk) * 64))[l];
            else if (l < 20) stg = ((const float4*)(ufk + (size_t)(r * NU + u_n) * 16))[l - 16];
            else if (l < 24) stg = ((const float4*)(mfk + (size_t)(r * NM + m_n) * 16))[l - 20];
        }

        const float w = __shfl(w8, j);
        const float wn = w / sqrtf(nrm_u[u] * nrm_m[m]);

        // compute from buffer j&1 (broadcast ds_reads, conflict-free)
        const float* L = &lds[wv][j & 1][0];
        const float4 a0 = ((const float4*)L)[q * 4 + 0];
        const float4 a1 = ((const float4*)L)[q * 4 + 1];
        const float4 a2 = ((const float4*)L)[q * 4 + 2];
        const float4 a3 = ((const float4*)L)[q * 4 + 3];
        const float4 uf = ((const float4*)L)[16 + q];
        const float4 mf = ((const float4*)L)[20 + q];

        float am = dot4(a0, wf0) + dot4(a1, wf1) + dot4(a2, wf2) + dot4(a3, wf3)
                 + dot4(uf, nf);
        float au = dot4(a0, wr0) + dot4(a1, wr1) + dot4(a2, wr2) + dot4(a3, wr3)
                 + dot4(mf, nr);
        am += __shfl_xor(am, 16); am += __shfl_xor(am, 32);
        au += __shfl_xor(au, 16); au += __shfl_xor(au, 32);
        am *= wn; au *= wn;

        if (l == j) wn8 = wn;

        if (live && l < 32) {   // single 32-lane atomic instruction
            float  val  = (l < 16) ? am : au;
            float* base = (l < 16) ? &ipre[(size_t)m * 16 + o]
                                   : &upre[(size_t)u * 16 + o];
            atomicAdd(base, val);
        }

        // write next edge's packet (vmcnt wait hidden under compute above)
        if (j + 1 < EPW && l < 24)
            ((float4*)&lds[wv][(j + 1) & 1][0])[l] = stg;
    }

    if (l < EPW && ebase + l < EDGES)
        dist_out[rE + ebase + l] = wn8;   // one coalesced 32B store per wave
}

// Fused leaky-relu + (N,16) x (16,64) FC for both tables.
__global__ __launch_bounds__(256) void k_fc(
    const float* __restrict__ upre, const float* __restrict__ ipre,
    const float* __restrict__ uw, const float* __restrict__ ub,
    const float* __restrict__ iw, const float* __restrict__ ib,
    float* __restrict__ out_u, float* __restrict__ out_i)
{
    const int tid = threadIdx.x;
    const int n = blockIdx.x * 4 + (tid >> 6);
    if (n >= NU + NM) return;
    const int o = tid & 63;
    const float* pre; const float* W; const float* B; float* dst;
    if (n < NU) { pre = upre + (size_t)n * 16; W = uw; B = ub; dst = out_u + (size_t)n * 64; }
    else { int n2 = n - NU; pre = ipre + (size_t)n2 * 16; W = iw; B = ib; dst = out_i + (size_t)n2 * 64; }
    float acc = B[o];
#pragma unroll
    for (int d = 0; d < 16; d++) {
        float x = pre[d];
        x = x >= 0.f ? x : 0.1f * x;
        acc += x * W[o * 16 + d];
    }
    dst[o] = acc;
}

extern "C" void kernel_launch(void* const* d_in, const int* in_sizes, int n_in,
                              void* d_out, int out_size, void* d_ws, size_t ws_size,
                              hipStream_t stream) {
    const float* ufk  = (const float*)d_in[0];
    const float* mfk  = (const float*)d_in[1];
    const float* ufs  = (const float*)d_in[2];
    const float* mfs  = (const float*)d_in[3];
    const float* rfe  = (const float*)d_in[4];
    const float* pro  = (const float*)d_in[5];
    const float* eta  = (const float*)d_in[6];
    const float* nwf  = (const float*)d_in[7];
    const float* rwf  = (const float*)d_in[8];
    const float* nwr  = (const float*)d_in[9];
    const float* rwr  = (const float*)d_in[10];
    const float* uw   = (const float*)d_in[11];
    const float* ub   = (const float*)d_in[12];
    const float* iw   = (const float*)d_in[13];
    const float* ib   = (const float*)d_in[14];
    const int*   eu   = (const int*)d_in[15];
    const int*   em   = (const int*)d_in[16];
    const int*   kp   = (const int*)d_in[17];

    float* out    = (float*)d_out;
    float* out_u  = out;                         // NU*64
    float* out_i  = out + (size_t)NU * 64;       // NM*64
    float* out_d  = out_i + (size_t)NM * 64;     // R*E

    float* ws    = (float*)d_ws;
    float* nrm_u = ws;                           // NU
    float* nrm_m = nrm_u + NU;                   // NM
    float* upre  = nrm_m + NM;                   // NU*16
    float* ipre  = upre + (size_t)NU * 16;       // NM*16
    float* wbuf  = ipre + (size_t)NM * 16;       // R*E

    const size_t zeroN = (size_t)NU + NM + (size_t)NU * 16 + (size_t)NM * 16;
    hipMemsetAsync(d_ws, 0, zeroN * sizeof(float), stream);

    dim3 gW((EDGES + 3) / 4, R_);
    k_edge_w<<<gW, 256, 0, stream>>>(ufk, mfk, ufs, mfs, rfe, pro, eta, eu, em, kp,
                                     wbuf, nrm_u, nrm_m);
    dim3 gM((EDGES + 4 * EPW - 1) / (4 * EPW), R_);
    k_edge_msg<<<gM, 256, 0, stream>>>(ufk, mfk, rfe, nwf, rwf, nwr, rwr, eu, em, kp,
                                       wbuf, nrm_u, nrm_m, upre, ipre, out_d);
    k_fc<<<((NU + NM) + 3) / 4, 256, 0, stream>>>(upre, ipre, uw, ub, iw, ib, out_u, out_i);
}

// Round 10
// 335.301 us; speedup vs baseline: 1.9447x; 1.2458x over previous
//
#include <hip/hip_runtime.h>

#define TAU_INV 2.0f
#define R_ 5
#define NU 50000
#define NM 20000
#define EDGES 100000
#define F_ 4
#define D_ 16
#define DR 64
#define OUT_ 64
#define EPW 8   // edges per wave in k_edge_msg

__device__ __forceinline__ float red16(float v) {
    v += __shfl_xor(v, 1);
    v += __shfl_xor(v, 2);
    v += __shfl_xor(v, 4);
    v += __shfl_xor(v, 8);
    return v;
}

__device__ __forceinline__ float dot4(float4 a, float4 b) {
    return a.x * b.x + a.y * b.y + a.z * b.z + a.w * b.w;
}

// One wave (64 lanes) per edge. Computes gating weight w, accumulates segment norms.
__global__ __launch_bounds__(256) void k_edge_w(
    const float* __restrict__ ufk, const float* __restrict__ mfk,
    const float* __restrict__ ufs, const float* __restrict__ mfs,
    const float* __restrict__ rfeat, const float* __restrict__ proto,
    const float* __restrict__ eta, const int* __restrict__ eu,
    const int* __restrict__ em, const int* __restrict__ kp,
    float* __restrict__ wbuf, float* __restrict__ nrm_u, float* __restrict__ nrm_m)
{
    const int wv = threadIdx.x >> 6, l = threadIdx.x & 63;
    const int e = blockIdx.x * 4 + wv;
    if (e >= EDGES) return;
    const int r = blockIdx.y;
    const int idx = r * EDGES + e;
    const int u = eu[idx], m = em[idx];
    const int kk = kp[0];

    // ---- sim_all: per-f dot over d (flat F*d = 64, lane l -> f = l>>4) ----
    float a = ufs[(size_t)(r * NU + u) * 64 + l] * mfs[(size_t)(r * NM + m) * 64 + l];
    a = red16(a);                       // each lane: raw dot sim_all[f]
    float es = expf(a * TAU_INV);
    float dsim = es + __shfl_xor(es, 16);
    dsim += __shfl_xor(dsim, 32);       // sum_f exp(sim_all[f]/TAU), all lanes

    // ---- sim_k: l2norm'd dot over d=16 (groups redundant) ----
    float uk = ufk[(size_t)(r * NU + u) * 16 + (l & 15)];
    float mk = mfk[(size_t)(r * NM + m) * 16 + (l & 15)];
    float su = red16(uk * uk);
    float sm = red16(mk * mk);
    float sd = red16(uk * mk);
    float nsim = expf(sd / (fmaxf(sqrtf(su), 1e-12f) * fmaxf(sqrtf(sm), 1e-12f)) * TAU_INV);

    // ---- anchor: review_feat row (F*Dr = 256 floats, coalesced float4/lane) ----
    const float4 rf = ((const float4*)(rfeat + (size_t)idx * 256))[l];
    const float4 pr = ((const float4*)proto)[l];
    float ap = dot4(rf, pr);
    ap = red16(ap);                     // lane -> ad_all[f=l>>4] (raw dot)
    float ea = expf(ap * TAU_INV);
    float dan = ea + __shfl_xor(ea, 16);
    dan += __shfl_xor(dan, 32);
    float adk = __shfl(ap, kk << 4);    // ad_all[k]
    float na = expf(adk * TAU_INV);

    float g = 1.0f / (1.0f + expf(-eta[idx]));
    float w = g * (na / dan) + (1.0f - g) * (nsim / dsim);

    if (l == 0) {
        wbuf[idx] = w;
        atomicAdd(&nrm_u[u], w);
        atomicAdd(&nrm_m[m], w);
    }
}

// One wave per EPW=8 edges, DEPTH-8 pipeline: all 8 edges' packets (8 x 384B =
// 3 float4/lane) loaded in one burst (192 loads in flight/wave), nrm values
// prefetched in header. NOTE: all __shfl calls are at full wave convergence
// (hoisted OUT of divergent branches — ds_bpermute from an inactive lane is
// undefined; this was round 8's correctness bug).
__global__ __launch_bounds__(256) void k_edge_msg(
    const float* __restrict__ ufk, const float* __restrict__ mfk,
    const float* __restrict__ rfeat,
    const float* __restrict__ nwf, const float* __restrict__ rwf,
    const float* __restrict__ nwr, const float* __restrict__ rwr,
    const int* __restrict__ eu, const int* __restrict__ em, const int* __restrict__ kp,
    const float* __restrict__ wbuf, const float* __restrict__ nrm_u,
    const float* __restrict__ nrm_m,
    float* __restrict__ upre, float* __restrict__ ipre, float* __restrict__ dist_out)
{
    __shared__ __align__(16) float4 lds[4][192]; // 12 KB: per wave, 8 edges x 24 float4

    const int tid = threadIdx.x;
    const int wv = tid >> 6, l = tid & 63;
    const int o = l & 15, q = l >> 4;
    const int r = blockIdx.y;
    const int kk = kp[0];
    const int rE = r * EDGES;

    // weights for (output o, input-quarter q) in registers
    const float4* pwf = (const float4*)(rwf + (size_t)r * 1024 + o * 64 + q * 16);
    const float4* pwr = (const float4*)(rwr + (size_t)r * 1024 + o * 64 + q * 16);
    const float4 wf0 = pwf[0], wf1 = pwf[1], wf2 = pwf[2], wf3 = pwf[3];
    const float4 wr0 = pwr[0], wr1 = pwr[1], wr2 = pwr[2], wr3 = pwr[3];
    const float4 nf = *(const float4*)(nwf + r * 256 + o * 16 + q * 4);
    const float4 nr = *(const float4*)(nwr + r * 256 + o * 16 + q * 4);

    const int ebase = (blockIdx.x * 4 + wv) * EPW;

    // header: lane group (l&7)=j holds edge ebase+j's ids / weight / norms
    int eu8, em8; float w8, wn8;
    {
        int e2 = ebase + (l & 7); if (e2 >= EDGES) e2 = EDGES - 1;
        eu8 = eu[rE + e2]; em8 = em[rE + e2]; w8 = wbuf[rE + e2];
        const float nu = nrm_u[eu8], nm = nrm_m[em8];
        wn8 = w8 / sqrtf(nu * nm);
    }

    // ---- stage ALL 8 edges: 192 float4 slots; lane l owns slots l, l+64, l+128 ----
    float4 st[3];
#pragma unroll
    for (int t = 0; t < 3; ++t) {
        const int s = l + 64 * t;
        const int j = s / 24;            // edge index 0..7
        const int p = s % 24;            // packet part: rf[0..15] | ufk[16..19] | mfk[20..23]
        int e2 = ebase + j; if (e2 >= EDGES) e2 = EDGES - 1;
        // shuffles at FULL convergence (all 64 lanes) — then select divergently
        const int uj = __shfl(eu8, j);
        const int mj = __shfl(em8, j);
        const float4* src;
        if (p < 16)      src = (const float4*)(rfeat + ((size_t)(rE + e2) * 4 + kk) * 64) + p;
        else if (p < 20) src = (const float4*)(ufk + (size_t)(r * NU + uj) * 16) + (p - 16);
        else             src = (const float4*)(mfk + (size_t)(r * NM + mj) * 16) + (p - 20);
        st[t] = *src;
    }
#pragma unroll
    for (int t = 0; t < 3; ++t)
        lds[wv][l + 64 * t] = st[t];

    // ---- compute 8 edges from LDS (no global loads in the loop) ----
#pragma unroll
    for (int j = 0; j < EPW; ++j) {
        const float4* L = &lds[wv][j * 24];
        const float4 a0 = L[q * 4 + 0];
        const float4 a1 = L[q * 4 + 1];
        const float4 a2 = L[q * 4 + 2];
        const float4 a3 = L[q * 4 + 3];
        const float4 uf = L[16 + q];
        const float4 mf = L[20 + q];

        float am = dot4(a0, wf0) + dot4(a1, wf1) + dot4(a2, wf2) + dot4(a3, wf3)
                 + dot4(uf, nf);
        float au = dot4(a0, wr0) + dot4(a1, wr1) + dot4(a2, wr2) + dot4(a3, wr3)
                 + dot4(mf, nr);
        am += __shfl_xor(am, 16); am += __shfl_xor(am, 32);
        au += __shfl_xor(au, 16); au += __shfl_xor(au, 32);

        const float wn = __shfl(wn8, j);
        am *= wn; au *= wn;

        const int u = __shfl(eu8, j), m = __shfl(em8, j);
        if ((ebase + j) < EDGES && l < 32) {   // single 32-lane atomic instruction
            float  val  = (l < 16) ? am : au;
            float* base = (l < 16) ? &ipre[(size_t)m * 16 + o]
                                   : &upre[(size_t)u * 16 + o];
            atomicAdd(base, val);
        }
    }

    if (l < EPW && ebase + l < EDGES)
        dist_out[rE + ebase + l] = wn8;   // one coalesced 32B store per wave
}

// Fused leaky-relu + (N,16) x (16,64) FC for both tables.
__global__ __launch_bounds__(256) void k_fc(
    const float* __restrict__ upre, const float* __restrict__ ipre,
    const float* __restrict__ uw, const float* __restrict__ ub,
    const float* __restrict__ iw, const float* __restrict__ ib,
    float* __restrict__ out_u, float* __restrict__ out_i)
{
    const int tid = threadIdx.x;
    const int n = blockIdx.x * 4 + (tid >> 6);
    if (n >= NU + NM) return;
    const int o = tid & 63;
    const float* pre; const float* W; const float* B; float* dst;
    if (n < NU) { pre = upre + (size_t)n * 16; W = uw; B = ub; dst = out_u + (size_t)n * 64; }
    else { int n2 = n - NU; pre = ipre + (size_t)n2 * 16; W = iw; B = ib; dst = out_i + (size_t)n2 * 64; }
    float acc = B[o];
#pragma unroll
    for (int d = 0; d < 16; d++) {
        float x = pre[d];
        x = x >= 0.f ? x : 0.1f * x;
        acc += x * W[o * 16 + d];
    }
    dst[o] = acc;
}

extern "C" void kernel_launch(void* const* d_in, const int* in_sizes, int n_in,
                              void* d_out, int out_size, void* d_ws, size_t ws_size,
                              hipStream_t stream) {
    const float* ufk  = (const float*)d_in[0];
    const float* mfk  = (const float*)d_in[1];
    const float* ufs  = (const float*)d_in[2];
    const float* mfs  = (const float*)d_in[3];
    const float* rfe  = (const float*)d_in[4];
    const float* pro  = (const float*)d_in[5];
    const float* eta  = (const float*)d_in[6];
    const float* nwf  = (const float*)d_in[7];
    const float* rwf  = (const float*)d_in[8];
    const float* nwr  = (const float*)d_in[9];
    const float* rwr  = (const float*)d_in[10];
    const float* uw   = (const float*)d_in[11];
    const float* ub   = (const float*)d_in[12];
    const float* iw   = (const float*)d_in[13];
    const float* ib   = (const float*)d_in[14];
    const int*   eu   = (const int*)d_in[15];
    const int*   em   = (const int*)d_in[16];
    const int*   kp   = (const int*)d_in[17];

    float* out    = (float*)d_out;
    float* out_u  = out;                         // NU*64
    float* out_i  = out + (size_t)NU * 64;       // NM*64
    float* out_d  = out_i + (size_t)NM * 64;     // R*E

    float* ws    = (float*)d_ws;
    float* nrm_u = ws;                           // NU
    float* nrm_m = nrm_u + NU;                   // NM
    float* upre  = nrm_m + NM;                   // NU*16
    float* ipre  = upre + (size_t)NU * 16;       // NM*16
    float* wbuf  = ipre + (size_t)NM * 16;       // R*E

    const size_t zeroN = (size_t)NU + NM + (size_t)NU * 16 + (size_t)NM * 16;
    hipMemsetAsync(d_ws, 0, zeroN * sizeof(float), stream);

    dim3 gW((EDGES + 3) / 4, R_);
    k_edge_w<<<gW, 256, 0, stream>>>(ufk, mfk, ufs, mfs, rfe, pro, eta, eu, em, kp,
                                     wbuf, nrm_u, nrm_m);
    dim3 gM((EDGES + 4 * EPW - 1) / (4 * EPW), R_);
    k_edge_msg<<<gM, 256, 0, stream>>>(ufk, mfk, rfe, nwf, rwf, nwr, rwr, eu, em, kp,
                                       wbuf, nrm_u, nrm_m, upre, ipre, out_d);
    k_fc<<<((NU + NM) + 3) / 4, 256, 0, stream>>>(upre, ipre, uw, ub, iw, ib, out_u, out_i);
}

// Round 11
// 323.560 us; speedup vs baseline: 2.0152x; 1.0363x over previous
//
#include <hip/hip_runtime.h>

#define TAU_INV 2.0f
#define R_ 5
#define NU 50000
#define NM 20000
#define EDGES 100000
#define F_ 4
#define D_ 16
#define DR 64
#define OUT_ 64
#define EPW 16  // edges per wave in k_edge_msg

__device__ __forceinline__ float red16(float v) {
    v += __shfl_xor(v, 1);
    v += __shfl_xor(v, 2);
    v += __shfl_xor(v, 4);
    v += __shfl_xor(v, 8);
    return v;
}

__device__ __forceinline__ float dot4(float4 a, float4 b) {
    return a.x * b.x + a.y * b.y + a.z * b.z + a.w * b.w;
}

// One wave (64 lanes) per edge. Computes gating weight w, accumulates segment norms.
__global__ __launch_bounds__(256) void k_edge_w(
    const float* __restrict__ ufk, const float* __restrict__ mfk,
    const float* __restrict__ ufs, const float* __restrict__ mfs,
    const float* __restrict__ rfeat, const float* __restrict__ proto,
    const float* __restrict__ eta, const int* __restrict__ eu,
    const int* __restrict__ em, const int* __restrict__ kp,
    float* __restrict__ wbuf, float* __restrict__ nrm_u, float* __restrict__ nrm_m)
{
    const int wv = threadIdx.x >> 6, l = threadIdx.x & 63;
    const int e = blockIdx.x * 4 + wv;
    if (e >= EDGES) return;
    const int r = blockIdx.y;
    const int idx = r * EDGES + e;
    const int u = eu[idx], m = em[idx];
    const int kk = kp[0];

    // ---- sim_all: per-f dot over d (flat F*d = 64, lane l -> f = l>>4) ----
    float a = ufs[(size_t)(r * NU + u) * 64 + l] * mfs[(size_t)(r * NM + m) * 64 + l];
    a = red16(a);                       // each lane: raw dot sim_all[f]
    float es = expf(a * TAU_INV);
    float dsim = es + __shfl_xor(es, 16);
    dsim += __shfl_xor(dsim, 32);       // sum_f exp(sim_all[f]/TAU), all lanes

    // ---- sim_k: l2norm'd dot over d=16 (groups redundant) ----
    float uk = ufk[(size_t)(r * NU + u) * 16 + (l & 15)];
    float mk = mfk[(size_t)(r * NM + m) * 16 + (l & 15)];
    float su = red16(uk * uk);
    float sm = red16(mk * mk);
    float sd = red16(uk * mk);
    float nsim = expf(sd / (fmaxf(sqrtf(su), 1e-12f) * fmaxf(sqrtf(sm), 1e-12f)) * TAU_INV);

    // ---- anchor: review_feat row (F*Dr = 256 floats, coalesced float4/lane) ----
    const float4 rf = ((const float4*)(rfeat + (size_t)idx * 256))[l];
    const float4 pr = ((const float4*)proto)[l];
    float ap = dot4(rf, pr);
    ap = red16(ap);                     // lane -> ad_all[f=l>>4] (raw dot)
    float ea = expf(ap * TAU_INV);
    float dan = ea + __shfl_xor(ea, 16);
    dan += __shfl_xor(dan, 32);
    float adk = __shfl(ap, kk << 4);    // ad_all[k]
    float na = expf(adk * TAU_INV);

    float g = 1.0f / (1.0f + expf(-eta[idx]));
    float w = g * (na / dan) + (1.0f - g) * (nsim / dsim);

    if (l == 0) {
        wbuf[idx] = w;
        atomicAdd(&nrm_u[u], w);
        atomicAdd(&nrm_m[m], w);
    }
}

// One wave per EPW=16 edges, depth-16 pipeline: all 16 edges' packets (16 x 384B
// = 6 float4/lane) loaded in one burst, nrm prefetched. Atomics PAIRED: one
// 64-lane atomic instruction scatters TWO edges (lanes 0-31 edge j, 32-63 edge
// j+1) — half the atomic instructions of round 10. All __shfl at full wave
// convergence (divergent-shfl was round 8's bug).
__global__ __launch_bounds__(256) void k_edge_msg(
    const float* __restrict__ ufk, const float* __restrict__ mfk,
    const float* __restrict__ rfeat,
    const float* __restrict__ nwf, const float* __restrict__ rwf,
    const float* __restrict__ nwr, const float* __restrict__ rwr,
    const int* __restrict__ eu, const int* __restrict__ em, const int* __restrict__ kp,
    const float* __restrict__ wbuf, const float* __restrict__ nrm_u,
    const float* __restrict__ nrm_m,
    float* __restrict__ upre, float* __restrict__ ipre, float* __restrict__ dist_out)
{
    __shared__ __align__(16) float4 lds[4][EPW * 24]; // 24.6 KB: per wave, 16 edges x 24 float4

    const int tid = threadIdx.x;
    const int wv = tid >> 6, l = tid & 63;
    const int o = l & 15, q = l >> 4;
    const int r = blockIdx.y;
    const int kk = kp[0];
    const int rE = r * EDGES;

    // weights for (output o, input-quarter q) in registers
    const float4* pwf = (const float4*)(rwf + (size_t)r * 1024 + o * 64 + q * 16);
    const float4* pwr = (const float4*)(rwr + (size_t)r * 1024 + o * 64 + q * 16);
    const float4 wf0 = pwf[0], wf1 = pwf[1], wf2 = pwf[2], wf3 = pwf[3];
    const float4 wr0 = pwr[0], wr1 = pwr[1], wr2 = pwr[2], wr3 = pwr[3];
    const float4 nf = *(const float4*)(nwf + r * 256 + o * 16 + q * 4);
    const float4 nr = *(const float4*)(nwr + r * 256 + o * 16 + q * 4);

    const int ebase = (blockIdx.x * 4 + wv) * EPW;

    // header: lane group (l&15)=j holds edge ebase+j's ids / weight / norms
    int eu16, em16; float wn16;
    {
        int e2 = ebase + (l & 15); if (e2 >= EDGES) e2 = EDGES - 1;
        eu16 = eu[rE + e2]; em16 = em[rE + e2];
        const float w0 = wbuf[rE + e2];
        wn16 = w0 / sqrtf(nrm_u[eu16] * nrm_m[em16]);
    }

    if (l < EPW && ebase + l < EDGES)
        dist_out[rE + ebase + l] = wn16;  // one coalesced 64B store per wave

    // ---- stage ALL 16 edges: 384 float4 slots; lane l owns slots l+64t, t<6 ----
    float4 st[6];
#pragma unroll
    for (int t = 0; t < 6; ++t) {
        const int s = l + 64 * t;
        const int j = s / 24;            // edge index 0..15 (per-lane)
        const int p = s % 24;            // rf[0..15] | ufk[16..19] | mfk[20..23]
        int e2 = ebase + j; if (e2 >= EDGES) e2 = EDGES - 1;
        // shuffles at FULL convergence — then select divergently
        const int uj = __shfl(eu16, j);
        const int mj = __shfl(em16, j);
        const float4* src;
        if (p < 16)      src = (const float4*)(rfeat + ((size_t)(rE + e2) * 4 + kk) * 64) + p;
        else if (p < 20) src = (const float4*)(ufk + (size_t)(r * NU + uj) * 16) + (p - 16);
        else             src = (const float4*)(mfk + (size_t)(r * NM + mj) * 16) + (p - 20);
        st[t] = *src;
    }
#pragma unroll
    for (int t = 0; t < 6; ++t)
        lds[wv][l + 64 * t] = st[t];

    // ---- compute 16 edges, 2 at a time; one 64-lane atomic per PAIR ----
#pragma unroll
    for (int j = 0; j < EPW; j += 2) {
        float amv[2], auv[2];
#pragma unroll
        for (int s = 0; s < 2; ++s) {
            const float4* L = &lds[wv][(j + s) * 24];
            const float4 a0 = L[q * 4 + 0];
            const float4 a1 = L[q * 4 + 1];
            const float4 a2 = L[q * 4 + 2];
            const float4 a3 = L[q * 4 + 3];
            const float4 uf = L[16 + q];
            const float4 mf = L[20 + q];

            float am = dot4(a0, wf0) + dot4(a1, wf1) + dot4(a2, wf2) + dot4(a3, wf3)
                     + dot4(uf, nf);
            float au = dot4(a0, wr0) + dot4(a1, wr1) + dot4(a2, wr2) + dot4(a3, wr3)
                     + dot4(mf, nr);
            am += __shfl_xor(am, 16); am += __shfl_xor(am, 32);
            au += __shfl_xor(au, 16); au += __shfl_xor(au, 32);
            const float wn = __shfl(wn16, j + s);
            amv[s] = am * wn; auv[s] = au * wn;
        }

        // all shuffles above at full convergence; ids too:
        const int u0 = __shfl(eu16, j),     m0 = __shfl(em16, j);
        const int u1 = __shfl(eu16, j + 1), m1 = __shfl(em16, j + 1);

        const int  half = l >> 5;             // 0: edge j, 1: edge j+1
        const bool liveA = (ebase + j + half) < EDGES;
        float  val;
        float* base;
        if (half == 0) {
            val  = (l < 16) ? amv[0] : auv[0];
            base = (l < 16) ? &ipre[(size_t)m0 * 16 + o] : &upre[(size_t)u0 * 16 + o];
        } else {
            val  = (l < 48) ? amv[1] : auv[1];
            base = (l < 48) ? &ipre[(size_t)m1 * 16 + o] : &upre[(size_t)u1 * 16 + o];
        }
        if (liveA) atomicAdd(base, val);
    }
}

// Fused leaky-relu + (N,16) x (16,64) FC for both tables.
__global__ __launch_bounds__(256) void k_fc(
    const float* __restrict__ upre, const float* __restrict__ ipre,
    const float* __restrict__ uw, const float* __restrict__ ub,
    const float* __restrict__ iw, const float* __restrict__ ib,
    float* __restrict__ out_u, float* __restrict__ out_i)
{
    const int tid = threadIdx.x;
    const int n = blockIdx.x * 4 + (tid >> 6);
    if (n >= NU + NM) return;
    const int o = tid & 63;
    const float* pre; const float* W; const float* B; float* dst;
    if (n < NU) { pre = upre + (size_t)n * 16; W = uw; B = ub; dst = out_u + (size_t)n * 64; }
    else { int n2 = n - NU; pre = ipre + (size_t)n2 * 16; W = iw; B = ib; dst = out_i + (size_t)n2 * 64; }
    float acc = B[o];
#pragma unroll
    for (int d = 0; d < 16; d++) {
        float x = pre[d];
        x = x >= 0.f ? x : 0.1f * x;
        acc += x * W[o * 16 + d];
    }
    dst[o] = acc;
}

extern "C" void kernel_launch(void* const* d_in, const int* in_sizes, int n_in,
                              void* d_out, int out_size, void* d_ws, size_t ws_size,
                              hipStream_t stream) {
    const float* ufk  = (const float*)d_in[0];
    const float* mfk  = (const float*)d_in[1];
    const float* ufs  = (const float*)d_in[2];
    const float* mfs  = (const float*)d_in[3];
    const float* rfe  = (const float*)d_in[4];
    const float* pro  = (const float*)d_in[5];
    const float* eta  = (const float*)d_in[6];
    const float* nwf  = (const float*)d_in[7];
    const float* rwf  = (const float*)d_in[8];
    const float* nwr  = (const float*)d_in[9];
    const float* rwr  = (const float*)d_in[10];
    const float* uw   = (const float*)d_in[11];
    const float* ub   = (const float*)d_in[12];
    const float* iw   = (const float*)d_in[13];
    const float* ib   = (const float*)d_in[14];
    const int*   eu   = (const int*)d_in[15];
    const int*   em   = (const int*)d_in[16];
    const int*   kp   = (const int*)d_in[17];

    float* out    = (float*)d_out;
    float* out_u  = out;                         // NU*64
    float* out_i  = out + (size_t)NU * 64;       // NM*64
    float* out_d  = out_i + (size_t)NM * 64;     // R*E

    float* ws    = (float*)d_ws;
    float* nrm_u = ws;                           // NU
    float* nrm_m = nrm_u + NU;                   // NM
    float* upre  = nrm_m + NM;                   // NU*16
    float* ipre  = upre + (size_t)NU * 16;       // NM*16
    float* wbuf  = ipre + (size_t)NM * 16;       // R*E

    const size_t zeroN = (size_t)NU + NM + (size_t)NU * 16 + (size_t)NM * 16;
    hipMemsetAsync(d_ws, 0, zeroN * sizeof(float), stream);

    dim3 gW((EDGES + 3) / 4, R_);
    k_edge_w<<<gW, 256, 0, stream>>>(ufk, mfk, ufs, mfs, rfe, pro, eta, eu, em, kp,
                                     wbuf, nrm_u, nrm_m);
    dim3 gM((EDGES + 4 * EPW - 1) / (4 * EPW), R_);
    k_edge_msg<<<gM, 256, 0, stream>>>(ufk, mfk, rfe, nwf, rwf, nwr, rwr, eu, em, kp,
                                       wbuf, nrm_u, nrm_m, upre, ipre, out_d);
    k_fc<<<((NU + NM) + 3) / 4, 256, 0, stream>>>(upre, ipre, uw, ub, iw, ib, out_u, out_i);
}

// Round 12
// 251.971 us; speedup vs baseline: 2.5878x; 1.2841x over previous
//
#include <hip/hip_runtime.h>

#define TAU_INV 2.0f
#define R_ 5
#define NU 50000
#define NM 20000
#define EDGES 100000
#define F_ 4
#define D_ 16
#define DR 64
#define OUT_ 64
#define EPW 16  // edges per wave in k_edge_msg

__device__ __forceinline__ float dot4(float4 a, float4 b) {
    return a.x * b.x + a.y * b.y + a.z * b.z + a.w * b.w;
}

// 4 edges per wave, 16 lanes per edge. ~4 shfl/edge (was ~25), float4 loads.
__global__ __launch_bounds__(256) void k_edge_w(
    const float* __restrict__ ufk, const float* __restrict__ mfk,
    const float* __restrict__ ufs, const float* __restrict__ mfs,
    const float* __restrict__ rfeat, const float* __restrict__ proto,
    const float* __restrict__ eta, const int* __restrict__ eu,
    const int* __restrict__ em, const int* __restrict__ kp,
    float* __restrict__ wbuf, float* __restrict__ nrm_u, float* __restrict__ nrm_m)
{
    const int tid = threadIdx.x;
    const int wv = tid >> 6, l = tid & 63;
    const int g16 = l >> 4;          // edge slot within wave
    const int j   = l & 15;          // lane within 16-lane group
    const int r = blockIdx.y;
    int e = (blockIdx.x * 4 + wv) * 4 + g16;
    const bool live = (e < EDGES);
    if (e >= EDGES) e = EDGES - 1;
    const int idx = r * EDGES + e;
    const int u = eu[idx], m = em[idx];
    const int kk = kp[0];

    // ---- sim_all: 64 floats; lane j dots float4 #j; f = j>>2 ----
    const float4 pu = ((const float4*)(ufs + (size_t)(r * NU + u) * 64))[j];
    const float4 pm = ((const float4*)(mfs + (size_t)(r * NM + m) * 64))[j];
    float p = dot4(pu, pm);
    p += __shfl_xor(p, 1); p += __shfl_xor(p, 2);      // per-f dot at subgroup
    const float es = expf(p * TAU_INV);
    float dsim = es;
    dsim += __shfl_xor(dsim, 4); dsim += __shfl_xor(dsim, 8);  // sum over f, all lanes

    // ---- sim_k: 16 floats; lanes use jc=j&3 (all 4 subgroups identical -> valid everywhere) ----
    const int jc = j & 3;
    const float4 u4 = ((const float4*)(ufk + (size_t)(r * NU + u) * 16))[jc];
    const float4 m4 = ((const float4*)(mfk + (size_t)(r * NM + m) * 16))[jc];
    float su = dot4(u4, u4), sm = dot4(m4, m4), sd = dot4(u4, m4);
    su += __shfl_xor(su, 1); su += __shfl_xor(su, 2);
    sm += __shfl_xor(sm, 1); sm += __shfl_xor(sm, 2);
    sd += __shfl_xor(sd, 1); sd += __shfl_xor(sd, 2);
    const float nsim = expf(sd / (fmaxf(sqrtf(su), 1e-12f) * fmaxf(sqrtf(sm), 1e-12f)) * TAU_INV);

    // ---- anchor: 256 floats; lane j handles f=j>>2, chunk c=j&3 (4 contig float4) ----
    const float4* rf4 = (const float4*)(rfeat + (size_t)idx * 256);
    const float4* pr4 = (const float4*)proto;
    const int base = (j >> 2) * 16 + (j & 3) * 4;
    float ap = 0.f;
#pragma unroll
    for (int t = 0; t < 4; ++t)
        ap += dot4(rf4[base + t], pr4[base + t]);
    ap += __shfl_xor(ap, 1); ap += __shfl_xor(ap, 2);  // f-dot at subgroup
    const float ea = expf(ap * TAU_INV);
    float dan = ea;
    dan += __shfl_xor(dan, 4); dan += __shfl_xor(dan, 8);
    const float adk = __shfl(ap, (l & 48) | (kk << 2)); // ad_all[k] (full convergence)
    const float na = expf(adk * TAU_INV);

    const float gt = 1.0f / (1.0f + expf(-eta[idx]));
    const float w = gt * (na / dan) + (1.0f - gt) * (nsim / dsim);

    if (live && j == 0) {
        wbuf[idx] = w;
        atomicAdd(&nrm_u[u], w);
        atomicAdd(&nrm_m[m], w);
    }
}

// One wave per EPW=16 edges, depth-16 pipeline: all 16 edges' packets (16 x 384B
// = 6 float4/lane) loaded in one burst, nrm prefetched. Atomics PAIRED: one
// 64-lane atomic instruction scatters TWO edges. All __shfl at full wave
// convergence (divergent-shfl was round 8's bug).
__global__ __launch_bounds__(256) void k_edge_msg(
    const float* __restrict__ ufk, const float* __restrict__ mfk,
    const float* __restrict__ rfeat,
    const float* __restrict__ nwf, const float* __restrict__ rwf,
    const float* __restrict__ nwr, const float* __restrict__ rwr,
    const int* __restrict__ eu, const int* __restrict__ em, const int* __restrict__ kp,
    const float* __restrict__ wbuf, const float* __restrict__ nrm_u,
    const float* __restrict__ nrm_m,
    float* __restrict__ upre, float* __restrict__ ipre, float* __restrict__ dist_out)
{
    __shared__ __align__(16) float4 lds[4][EPW * 24];

    const int tid = threadIdx.x;
    const int wv = tid >> 6, l = tid & 63;
    const int o = l & 15, q = l >> 4;
    const int r = blockIdx.y;
    const int kk = kp[0];
    const int rE = r * EDGES;

    const float4* pwf = (const float4*)(rwf + (size_t)r * 1024 + o * 64 + q * 16);
    const float4* pwr = (const float4*)(rwr + (size_t)r * 1024 + o * 64 + q * 16);
    const float4 wf0 = pwf[0], wf1 = pwf[1], wf2 = pwf[2], wf3 = pwf[3];
    const float4 wr0 = pwr[0], wr1 = pwr[1], wr2 = pwr[2], wr3 = pwr[3];
    const float4 nf = *(const float4*)(nwf + r * 256 + o * 16 + q * 4);
    const float4 nr = *(const float4*)(nwr + r * 256 + o * 16 + q * 4);

    const int ebase = (blockIdx.x * 4 + wv) * EPW;

    int eu16, em16; float wn16;
    {
        int e2 = ebase + (l & 15); if (e2 >= EDGES) e2 = EDGES - 1;
        eu16 = eu[rE + e2]; em16 = em[rE + e2];
        const float w0 = wbuf[rE + e2];
        wn16 = w0 / sqrtf(nrm_u[eu16] * nrm_m[em16]);
    }

    if (l < EPW && ebase + l < EDGES)
        dist_out[rE + ebase + l] = wn16;

    float4 st[6];
#pragma unroll
    for (int t = 0; t < 6; ++t) {
        const int s = l + 64 * t;
        const int j = s / 24;
        const int p = s % 24;
        int e2 = ebase + j; if (e2 >= EDGES) e2 = EDGES - 1;
        const int uj = __shfl(eu16, j);
        const int mj = __shfl(em16, j);
        const float4* src;
        if (p < 16)      src = (const float4*)(rfeat + ((size_t)(rE + e2) * 4 + kk) * 64) + p;
        else if (p < 20) src = (const float4*)(ufk + (size_t)(r * NU + uj) * 16) + (p - 16);
        else             src = (const float4*)(mfk + (size_t)(r * NM + mj) * 16) + (p - 20);
        st[t] = *src;
    }
#pragma unroll
    for (int t = 0; t < 6; ++t)
        lds[wv][l + 64 * t] = st[t];

#pragma unroll
    for (int j = 0; j < EPW; j += 2) {
        float amv[2], auv[2];
#pragma unroll
        for (int s = 0; s < 2; ++s) {
            const float4* L = &lds[wv][(j + s) * 24];
            const float4 a0 = L[q * 4 + 0];
            const float4 a1 = L[q * 4 + 1];
            const float4 a2 = L[q * 4 + 2];
            const float4 a3 = L[q * 4 + 3];
            const float4 uf = L[16 + q];
            const float4 mf = L[20 + q];

            float am = dot4(a0, wf0) + dot4(a1, wf1) + dot4(a2, wf2) + dot4(a3, wf3)
                     + dot4(uf, nf);
            float au = dot4(a0, wr0) + dot4(a1, wr1) + dot4(a2, wr2) + dot4(a3, wr3)
                     + dot4(mf, nr);
            am += __shfl_xor(am, 16); am += __shfl_xor(am, 32);
            au += __shfl_xor(au, 16); au += __shfl_xor(au, 32);
            const float wn = __shfl(wn16, j + s);
            amv[s] = am * wn; auv[s] = au * wn;
        }

        const int u0 = __shfl(eu16, j),     m0 = __shfl(em16, j);
        const int u1 = __shfl(eu16, j + 1), m1 = __shfl(em16, j + 1);

        const int  half = l >> 5;
        const bool liveA = (ebase + j + half) < EDGES;
        float  val;
        float* base;
        if (half == 0) {
            val  = (l < 16) ? amv[0] : auv[0];
            base = (l < 16) ? &ipre[(size_t)m0 * 16 + o] : &upre[(size_t)u0 * 16 + o];
        } else {
            val  = (l < 48) ? amv[1] : auv[1];
            base = (l < 48) ? &ipre[(size_t)m1 * 16 + o] : &upre[(size_t)u1 * 16 + o];
        }
        if (liveA) atomicAdd(base, val);
    }
}

// Fused leaky-relu + (N,16) x (16,64) FC for both tables.
__global__ __launch_bounds__(256) void k_fc(
    const float* __restrict__ upre, const float* __restrict__ ipre,
    const float* __restrict__ uw, const float* __restrict__ ub,
    const float* __restrict__ iw, const float* __restrict__ ib,
    float* __restrict__ out_u, float* __restrict__ out_i)
{
    const int tid = threadIdx.x;
    const int n = blockIdx.x * 4 + (tid >> 6);
    if (n >= NU + NM) return;
    const int o = tid & 63;
    const float* pre; const float* W; const float* B; float* dst;
    if (n < NU) { pre = upre + (size_t)n * 16; W = uw; B = ub; dst = out_u + (size_t)n * 64; }
    else { int n2 = n - NU; pre = ipre + (size_t)n2 * 16; W = iw; B = ib; dst = out_i + (size_t)n2 * 64; }
    float acc = B[o];
#pragma unroll
    for (int d = 0; d < 16; d++) {
        float x = pre[d];
        x = x >= 0.f ? x : 0.1f * x;
        acc += x * W[o * 16 + d];
    }
    dst[o] = acc;
}

extern "C" void kernel_launch(void* const* d_in, const int* in_sizes, int n_in,
                              void* d_out, int out_size, void* d_ws, size_t ws_size,
                              hipStream_t stream) {
    const float* ufk  = (const float*)d_in[0];
    const float* mfk  = (const float*)d_in[1];
    const float* ufs  = (const float*)d_in[2];
    const float* mfs  = (const float*)d_in[3];
    const float* rfe  = (const float*)d_in[4];
    const float* pro  = (const float*)d_in[5];
    const float* eta  = (const float*)d_in[6];
    const float* nwf  = (const float*)d_in[7];
    const float* rwf  = (const float*)d_in[8];
    const float* nwr  = (const float*)d_in[9];
    const float* rwr  = (const float*)d_in[10];
    const float* uw   = (const float*)d_in[11];
    const float* ub   = (const float*)d_in[12];
    const float* iw   = (const float*)d_in[13];
    const float* ib   = (const float*)d_in[14];
    const int*   eu   = (const int*)d_in[15];
    const int*   em   = (const int*)d_in[16];
    const int*   kp   = (const int*)d_in[17];

    float* out    = (float*)d_out;
    float* out_u  = out;                         // NU*64
    float* out_i  = out + (size_t)NU * 64;       // NM*64
    float* out_d  = out_i + (size_t)NM * 64;     // R*E

    float* ws    = (float*)d_ws;
    float* nrm_u = ws;                           // NU
    float* nrm_m = nrm_u + NU;                   // NM
    float* upre  = nrm_m + NM;                   // NU*16
    float* ipre  = upre + (size_t)NU * 16;       // NM*16
    float* wbuf  = ipre + (size_t)NM * 16;       // R*E

    const size_t zeroN = (size_t)NU + NM + (size_t)NU * 16 + (size_t)NM * 16;
    hipMemsetAsync(d_ws, 0, zeroN * sizeof(float), stream);

    dim3 gW((EDGES + 15) / 16, R_);
    k_edge_w<<<gW, 256, 0, stream>>>(ufk, mfk, ufs, mfs, rfe, pro, eta, eu, em, kp,
                                     wbuf, nrm_u, nrm_m);
    dim3 gM((EDGES + 4 * EPW - 1) / (4 * EPW), R_);
    k_edge_msg<<<gM, 256, 0, stream>>>(ufk, mfk, rfe, nwf, rwf, nwr, rwr, eu, em, kp,
                                       wbuf, nrm_u, nrm_m, upre, ipre, out_d);
    k_fc<<<((NU + NM) + 3) / 4, 256, 0, stream>>>(upre, ipre, uw, ub, iw, ib, out_u, out_i);
}